// Round 1
// 411.540 us; speedup vs baseline: 1.0458x; 1.0458x over previous
//
#include <hip/hip_runtime.h>
#include <math.h>

#define NV 8192
#define CAP 64

typedef __attribute__((ext_vector_type(8))) short short8;
typedef __attribute__((ext_vector_type(4))) float f32x4;

static __device__ __forceinline__ unsigned short f2bf(float v) {
  unsigned int u = __float_as_uint(v);
  unsigned int r = (u + 0x7fffu + ((u >> 16) & 1u)) >> 16;  // RNE
  return (unsigned short)r;
}
static __device__ __forceinline__ float bf2f(unsigned short h) {
  return __uint_as_float(((unsigned int)h) << 16);
}

// ---------------------------------------------------------------------------
// MEGA kernel: blocks 0..255 = GEMM1 (XW1 = x @ W1, split-bf16 MFMA, inline
// f32->hi/lo conversion during staging); blocks 256..8447 = build_graph
// (one pass over adj: ELL cols, popcount degree, diag flag).
// Build path now BATCHES the whole 32 KB row read (8 float4/thread) before
// the ballot/compaction work: 8 KB/wave in flight -> HBM-BW-bound instead of
// latency-marginal (Little's law needs ~22 KB/CU; previously ~20 KB/CU).
// ---------------------------------------------------------------------------
__global__ __launch_bounds__(256) void mega_build_gemm1(
    const float* __restrict__ adj, const float* __restrict__ x,
    const float* __restrict__ W1, int* __restrict__ cols,
    int* __restrict__ rowcount, float* __restrict__ dinv,
    float* __restrict__ diagv, float* __restrict__ XW1) {
  __shared__ __align__(16) unsigned short sAh[128][40];
  __shared__ __align__(16) unsigned short sAl[128][40];
  __shared__ __align__(16) unsigned short sBh[64][40];
  __shared__ __align__(16) unsigned short sBl[64][40];
  __shared__ int cnt;
  __shared__ int diag_nz;
  __shared__ int wsum[4];

  int t = threadIdx.x;
  int lane = t & 63;

  if (blockIdx.x < 256) {
    // ===================== GEMM1 path =====================
    const int K = 512;
    int b = blockIdx.x;
    int bn = (b & 3) * 64;
    int bm = (b >> 2) * 128;
    int w = t >> 6;
    int quad = lane >> 4, m16 = lane & 15;
    f32x4 acc[2][4] = {};
    for (int k0 = 0; k0 < K; k0 += 32) {
#pragma unroll
      for (int i = 0; i < 4; i++) {
        int id = t + i * 256;
        int row = id >> 3;
        int fq = id & 7;
        float4 v = *(const float4*)&x[(size_t)(bm + row) * K + k0 + fq * 4];
        ushort4 h, l;
        h.x = f2bf(v.x); l.x = f2bf(v.x - bf2f(h.x));
        h.y = f2bf(v.y); l.y = f2bf(v.y - bf2f(h.y));
        h.z = f2bf(v.z); l.z = f2bf(v.z - bf2f(h.z));
        h.w = f2bf(v.w); l.w = f2bf(v.w - bf2f(h.w));
        *(ushort4*)&sAh[row][fq * 4] = h;
        *(ushort4*)&sAl[row][fq * 4] = l;
      }
#pragma unroll
      for (int j = 0; j < 2; j++) {
        int id = t + j * 256;
        int k = id >> 4;
        int n4 = (id & 15) * 4;
        float4 v = *(const float4*)&W1[(size_t)(k0 + k) * 256 + bn + n4];
        float va[4] = {v.x, v.y, v.z, v.w};
#pragma unroll
        for (int c = 0; c < 4; c++) {
          unsigned short h = f2bf(va[c]);
          sBh[n4 + c][k] = h;
          sBl[n4 + c][k] = f2bf(va[c] - bf2f(h));
        }
      }
      __syncthreads();
      short8 ah[2], al[2], bh[4], bl[4];
#pragma unroll
      for (int i = 0; i < 2; i++) {
        ah[i] = *(const short8*)&sAh[w * 32 + i * 16 + m16][quad * 8];
        al[i] = *(const short8*)&sAl[w * 32 + i * 16 + m16][quad * 8];
      }
#pragma unroll
      for (int j = 0; j < 4; j++) {
        bh[j] = *(const short8*)&sBh[j * 16 + m16][quad * 8];
        bl[j] = *(const short8*)&sBl[j * 16 + m16][quad * 8];
      }
#pragma unroll
      for (int i = 0; i < 2; i++)
#pragma unroll
        for (int j = 0; j < 4; j++) {
          acc[i][j] = __builtin_amdgcn_mfma_f32_16x16x32_bf16(ah[i], bh[j], acc[i][j], 0, 0, 0);
          acc[i][j] = __builtin_amdgcn_mfma_f32_16x16x32_bf16(al[i], bh[j], acc[i][j], 0, 0, 0);
          acc[i][j] = __builtin_amdgcn_mfma_f32_16x16x32_bf16(ah[i], bl[j], acc[i][j], 0, 0, 0);
        }
      __syncthreads();
    }
#pragma unroll
    for (int i = 0; i < 2; i++)
#pragma unroll
      for (int j = 0; j < 4; j++)
#pragma unroll
        for (int r = 0; r < 4; r++)
          XW1[(size_t)(bm + w * 32 + i * 16 + quad * 4 + r) * 256 + bn + j * 16 + m16] =
              acc[i][j][r];
  } else {
    // ===================== build_graph path =====================
    int row = blockIdx.x - 256;
    if (t == 0) { cnt = 0; diag_nz = 0; }
    __syncthreads();
    const float4* arow = (const float4*)(adj + (size_t)row * NV);
    // Batch the whole 32 KB row: 8 independent float4 loads in flight per
    // thread BEFORE any dependent ballot work.
    float4 v0 = arow[t + 0 * 256];
    float4 v1 = arow[t + 1 * 256];
    float4 v2 = arow[t + 2 * 256];
    float4 v3 = arow[t + 3 * 256];
    float4 v4 = arow[t + 4 * 256];
    float4 v5 = arow[t + 5 * 256];
    float4 v6 = arow[t + 6 * 256];
    float4 v7 = arow[t + 7 * 256];
    int mycount = 0;
    float4 vv[8] = {v0, v1, v2, v3, v4, v5, v6, v7};
#pragma unroll
    for (int u = 0; u < 8; u++) {
      int i = t + u * 256;
      float va[4] = {vv[u].x, vv[u].y, vv[u].z, vv[u].w};
#pragma unroll
      for (int j = 0; j < 4; j++) {
        bool nz = (va[j] != 0.0f);
        mycount += nz ? 1 : 0;
        int c = i * 4 + j;
        bool isdiag = nz && (c == row);
        bool take = nz && !isdiag;
        if (isdiag) diag_nz = 1;
        unsigned long long m = __ballot(take);
        if (m != 0ull) {
          int tot = __popcll(m);
          int pre = __popcll(m & ((1ull << lane) - 1ull));
          int leader = __ffsll((unsigned long long)m) - 1;
          int base = 0;
          if (lane == leader) base = atomicAdd(&cnt, tot);
          base = __shfl(base, leader, 64);
          if (take) {
            int p = base + pre;
            if (p < CAP) cols[(size_t)row * CAP + p] = c;
          }
        }
      }
    }
    for (int off = 32; off > 0; off >>= 1) mycount += __shfl_xor(mycount, off, 64);
    if (lane == 0) wsum[t >> 6] = mycount;
    __syncthreads();
    if (t == 0) {
      int nnz = wsum[0] + wsum[1] + wsum[2] + wsum[3];
      float deg = (float)nnz + 1.0f;
      dinv[row] = 1.0f / sqrtf(deg);
      diagv[row] = diag_nz ? 2.0f : 1.0f;
      rowcount[row] = cnt > CAP ? CAP : cnt;
    }
  }
}

// ---------------------------------------------------------------------------
// Kernel C: layer-1 aggregate + relu. One WAVE per row, float4 per lane,
// unroll x8 -> 8 independent 1 KB gathers in flight (avg degree ~16 => two
// full batches); 4x and scalar tails.
// ---------------------------------------------------------------------------
__global__ __launch_bounds__(256) void spmm_relu_k(
    const float* __restrict__ Z, const int* __restrict__ cols,
    const int* __restrict__ rowcount, const float* __restrict__ dinv,
    const float* __restrict__ diagv, float* __restrict__ H) {
  int lane = threadIdx.x & 63;
  int row = blockIdx.x * 4 + (threadIdx.x >> 6);
  const float4* Zr = (const float4*)Z;
  float di = dinv[row];
  float4 z = Zr[(size_t)row * 64 + lane];
  float dd = diagv[row] * di;
  float4 acc;
  acc.x = dd * z.x; acc.y = dd * z.y; acc.z = dd * z.z; acc.w = dd * z.w;
  int cnt = rowcount[row];
  const int* cr = cols + (size_t)row * CAP;
  int e = 0;
  for (; e + 8 <= cnt; e += 8) {
    int c0 = cr[e + 0], c1 = cr[e + 1], c2 = cr[e + 2], c3 = cr[e + 3];
    int c4 = cr[e + 4], c5 = cr[e + 5], c6 = cr[e + 6], c7 = cr[e + 7];
    float w0 = dinv[c0], w1 = dinv[c1], w2 = dinv[c2], w3 = dinv[c3];
    float w4 = dinv[c4], w5 = dinv[c5], w6 = dinv[c6], w7 = dinv[c7];
    float4 g0 = Zr[(size_t)c0 * 64 + lane];
    float4 g1 = Zr[(size_t)c1 * 64 + lane];
    float4 g2 = Zr[(size_t)c2 * 64 + lane];
    float4 g3 = Zr[(size_t)c3 * 64 + lane];
    float4 g4 = Zr[(size_t)c4 * 64 + lane];
    float4 g5 = Zr[(size_t)c5 * 64 + lane];
    float4 g6 = Zr[(size_t)c6 * 64 + lane];
    float4 g7 = Zr[(size_t)c7 * 64 + lane];
    acc.x += w0 * g0.x + w1 * g1.x + w2 * g2.x + w3 * g3.x;
    acc.y += w0 * g0.y + w1 * g1.y + w2 * g2.y + w3 * g3.y;
    acc.z += w0 * g0.z + w1 * g1.z + w2 * g2.z + w3 * g3.z;
    acc.w += w0 * g0.w + w1 * g1.w + w2 * g2.w + w3 * g3.w;
    acc.x += w4 * g4.x + w5 * g5.x + w6 * g6.x + w7 * g7.x;
    acc.y += w4 * g4.y + w5 * g5.y + w6 * g6.y + w7 * g7.y;
    acc.z += w4 * g4.z + w5 * g5.z + w6 * g6.z + w7 * g7.z;
    acc.w += w4 * g4.w + w5 * g5.w + w6 * g6.w + w7 * g7.w;
  }
  for (; e + 4 <= cnt; e += 4) {
    int c0 = cr[e + 0], c1 = cr[e + 1], c2 = cr[e + 2], c3 = cr[e + 3];
    float w0 = dinv[c0], w1 = dinv[c1], w2 = dinv[c2], w3 = dinv[c3];
    float4 g0 = Zr[(size_t)c0 * 64 + lane];
    float4 g1 = Zr[(size_t)c1 * 64 + lane];
    float4 g2 = Zr[(size_t)c2 * 64 + lane];
    float4 g3 = Zr[(size_t)c3 * 64 + lane];
    acc.x += w0 * g0.x + w1 * g1.x + w2 * g2.x + w3 * g3.x;
    acc.y += w0 * g0.y + w1 * g1.y + w2 * g2.y + w3 * g3.y;
    acc.z += w0 * g0.z + w1 * g1.z + w2 * g2.z + w3 * g3.z;
    acc.w += w0 * g0.w + w1 * g1.w + w2 * g2.w + w3 * g3.w;
  }
  for (; e < cnt; e++) {
    int c = cr[e];
    float w = dinv[c];
    float4 g = Zr[(size_t)c * 64 + lane];
    acc.x += w * g.x; acc.y += w * g.y; acc.z += w * g.z; acc.w += w * g.w;
  }
  float4 o;
  o.x = fmaxf(acc.x * di, 0.0f);
  o.y = fmaxf(acc.y * di, 0.0f);
  o.z = fmaxf(acc.z * di, 0.0f);
  o.w = fmaxf(acc.w * di, 0.0f);
  ((float4*)H)[(size_t)row * 64 + lane] = o;
}

// ---------------------------------------------------------------------------
// Kernel D: layer-2 GEMM via split-bf16 MFMA. HW2[8192][64] = H @ W2 with
// cols 40..63 exact zeros (B staged as zero there). 256 blocks x 32-row
// tiles. Wave w: m-half = w&1 (16 rows), n-pair = (w>>1)*2. LDS ~15.4 KB.
// ---------------------------------------------------------------------------
__global__ __launch_bounds__(256) void gemm2_mfma(
    const float* __restrict__ H, const float* __restrict__ W2,
    float* __restrict__ HW2) {
  const int K = 256;
  __shared__ __align__(16) unsigned short sAh[32][40];
  __shared__ __align__(16) unsigned short sAl[32][40];
  __shared__ __align__(16) unsigned short sBh[64][40];
  __shared__ __align__(16) unsigned short sBl[64][40];
  int t = threadIdx.x;
  int bm = blockIdx.x * 32;
  int lane = t & 63, w = t >> 6;
  int quad = lane >> 4, m16 = lane & 15;
  int i = w & 1;          // m-half
  int jj = (w >> 1) * 2;  // first n-frag
  f32x4 acc[2] = {};
  for (int k0 = 0; k0 < K; k0 += 32) {
    {  // A tile: 32 rows x 32 k from H (f32), inline hi/lo split
      int row = t >> 3;        // 0..31
      int fq = t & 7;          // k = fq*4
      float4 v = *(const float4*)&H[(size_t)(bm + row) * K + k0 + fq * 4];
      ushort4 h, l;
      h.x = f2bf(v.x); l.x = f2bf(v.x - bf2f(h.x));
      h.y = f2bf(v.y); l.y = f2bf(v.y - bf2f(h.y));
      h.z = f2bf(v.z); l.z = f2bf(v.z - bf2f(h.z));
      h.w = f2bf(v.w); l.w = f2bf(v.w - bf2f(h.w));
      *(ushort4*)&sAh[row][fq * 4] = h;
      *(ushort4*)&sAl[row][fq * 4] = l;
    }
#pragma unroll
    for (int j = 0; j < 2; j++) {  // B tile: 64 n x 32 k from W2[k][n<40]
      int id = t + j * 256;        // 0..511
      int k = id >> 4;             // 0..31
      int n4 = (id & 15) * 4;      // 0..60
#pragma unroll
      for (int c = 0; c < 4; c++) {
        float v = (n4 + c < 40) ? W2[(size_t)(k0 + k) * 40 + n4 + c] : 0.0f;
        unsigned short h = f2bf(v);
        sBh[n4 + c][k] = h;
        sBl[n4 + c][k] = f2bf(v - bf2f(h));
      }
    }
    __syncthreads();
    short8 ah = *(const short8*)&sAh[i * 16 + m16][quad * 8];
    short8 al = *(const short8*)&sAl[i * 16 + m16][quad * 8];
#pragma unroll
    for (int jx = 0; jx < 2; jx++) {
      short8 bh = *(const short8*)&sBh[(jj + jx) * 16 + m16][quad * 8];
      short8 bl = *(const short8*)&sBl[(jj + jx) * 16 + m16][quad * 8];
      acc[jx] = __builtin_amdgcn_mfma_f32_16x16x32_bf16(ah, bh, acc[jx], 0, 0, 0);
      acc[jx] = __builtin_amdgcn_mfma_f32_16x16x32_bf16(al, bh, acc[jx], 0, 0, 0);
      acc[jx] = __builtin_amdgcn_mfma_f32_16x16x32_bf16(ah, bl, acc[jx], 0, 0, 0);
    }
    __syncthreads();
  }
#pragma unroll
  for (int jx = 0; jx < 2; jx++)
#pragma unroll
    for (int r = 0; r < 4; r++)
      HW2[(size_t)(bm + i * 16 + quad * 4 + r) * 64 + (jj + jx) * 16 + m16] =
          acc[jx][r];
}

// ---------------------------------------------------------------------------
// Kernel E: layer-2 aggregate + relu + log_softmax (wave per row, 64-wide
// padded HW2; cols 40..63 exact zeros from gemm2_mfma). Unroll x8 gathers.
// ---------------------------------------------------------------------------
__global__ __launch_bounds__(256) void spmm2_lsm_k(
    const float* __restrict__ Z, const int* __restrict__ cols,
    const int* __restrict__ rowcount, const float* __restrict__ dinv,
    const float* __restrict__ diagv, float* __restrict__ out) {
  int lane = threadIdx.x & 63;
  int row = blockIdx.x * 4 + (threadIdx.x >> 6);
  float di = dinv[row];
  float acc = diagv[row] * di * Z[(size_t)row * 64 + lane];
  int cnt = rowcount[row];
  const int* cr = cols + (size_t)row * CAP;
  int e = 0;
  for (; e + 8 <= cnt; e += 8) {
    int c0 = cr[e + 0], c1 = cr[e + 1], c2 = cr[e + 2], c3 = cr[e + 3];
    int c4 = cr[e + 4], c5 = cr[e + 5], c6 = cr[e + 6], c7 = cr[e + 7];
    float w0 = dinv[c0], w1 = dinv[c1], w2 = dinv[c2], w3 = dinv[c3];
    float w4 = dinv[c4], w5 = dinv[c5], w6 = dinv[c6], w7 = dinv[c7];
    float g0 = Z[(size_t)c0 * 64 + lane];
    float g1 = Z[(size_t)c1 * 64 + lane];
    float g2 = Z[(size_t)c2 * 64 + lane];
    float g3 = Z[(size_t)c3 * 64 + lane];
    float g4 = Z[(size_t)c4 * 64 + lane];
    float g5 = Z[(size_t)c5 * 64 + lane];
    float g6 = Z[(size_t)c6 * 64 + lane];
    float g7 = Z[(size_t)c7 * 64 + lane];
    acc += w0 * g0 + w1 * g1 + w2 * g2 + w3 * g3;
    acc += w4 * g4 + w5 * g5 + w6 * g6 + w7 * g7;
  }
  for (; e + 4 <= cnt; e += 4) {
    int c0 = cr[e + 0], c1 = cr[e + 1], c2 = cr[e + 2], c3 = cr[e + 3];
    float w0 = dinv[c0], w1 = dinv[c1], w2 = dinv[c2], w3 = dinv[c3];
    acc += w0 * Z[(size_t)c0 * 64 + lane] + w1 * Z[(size_t)c1 * 64 + lane] +
           w2 * Z[(size_t)c2 * 64 + lane] + w3 * Z[(size_t)c3 * 64 + lane];
  }
  for (; e < cnt; e++) {
    int c = cr[e];
    acc += dinv[c] * Z[(size_t)c * 64 + lane];
  }
  float h2 = (lane < 40) ? fmaxf(acc * di, 0.0f) : -INFINITY;
  float m = h2;
  for (int off = 32; off > 0; off >>= 1) m = fmaxf(m, __shfl_xor(m, off, 64));
  float ex = (lane < 40) ? expf(h2 - m) : 0.0f;
  float s = ex;
  for (int off = 32; off > 0; off >>= 1) s += __shfl_xor(s, off, 64);
  float ls = logf(s);
  if (lane < 40) out[(size_t)row * 40 + lane] = h2 - m - ls;
}

// ---------------------------------------------------------------------------
// Workspace (bytes, 16B-aligned):
//   cols @ 0 : 2097152        rowcount @ 2097152 : 32768
//   dinv @ 2129920 : 32768    diagv    @ 2162688 : 32768
//   XW1  @ 2195456 : 8388608  H        @ 10584064 : 8388608
//   HW2  @ 18972672 : 2097152 (8192 x 64, cols 40..63 zero)
// ---------------------------------------------------------------------------
extern "C" void kernel_launch(void* const* d_in, const int* in_sizes, int n_in,
                              void* d_out, int out_size, void* d_ws, size_t ws_size,
                              hipStream_t stream) {
  (void)in_sizes; (void)n_in; (void)out_size; (void)ws_size;
  const float* x   = (const float*)d_in[0];
  const float* adj = (const float*)d_in[1];
  const float* W1  = (const float*)d_in[2];
  const float* W2  = (const float*)d_in[3];
  float* out = (float*)d_out;
  char* ws = (char*)d_ws;

  int*   cols     = (int*)(ws);
  int*   rowcount = (int*)(ws + 2097152);
  float* dinv     = (float*)(ws + 2129920);
  float* diagv    = (float*)(ws + 2162688);
  float* XW1      = (float*)(ws + 2195456);
  float* H        = (float*)(ws + 10584064);
  float* HW2      = (float*)(ws + 18972672);

  hipLaunchKernelGGL(mega_build_gemm1, dim3(256 + NV), dim3(256), 0, stream,
                     adj, x, W1, cols, rowcount, dinv, diagv, XW1);
  hipLaunchKernelGGL(spmm_relu_k, dim3(NV / 4), dim3(256), 0, stream,
                     XW1, cols, rowcount, dinv, diagv, H);
  hipLaunchKernelGGL(gemm2_mfma, dim3(NV / 32), dim3(256), 0, stream,
                     H, W2, HW2);
  hipLaunchKernelGGL(spmm2_lsm_k, dim3(NV / 4), dim3(256), 0, stream,
                     HW2, cols, rowcount, dinv, diagv, out);
}

// Round 2
// 407.457 us; speedup vs baseline: 1.0563x; 1.0100x over previous
//
#include <hip/hip_runtime.h>
#include <math.h>

#define NV 8192
#define CAP 64

typedef __attribute__((ext_vector_type(8))) short short8;
typedef __attribute__((ext_vector_type(4))) float f32x4;

static __device__ __forceinline__ unsigned short f2bf(float v) {
  unsigned int u = __float_as_uint(v);
  unsigned int r = (u + 0x7fffu + ((u >> 16) & 1u)) >> 16;  // RNE
  return (unsigned short)r;
}
static __device__ __forceinline__ float bf2f(unsigned short h) {
  return __uint_as_float(((unsigned int)h) << 16);
}

// ---------------------------------------------------------------------------
// MEGA kernel: blocks 0..511 = GEMM1 (XW1 = x @ W1, split-bf16 MFMA, 64x64
// tiles -> LDS 20.5 KB -> 7 blocks/CU, up from 5 at 128x64);
// blocks 512..8703 = build_graph. Build path: batched 32 KB row read, then
// SCAN-BASED compaction (per-thread nz bitmask + one wave prefix scan + one
// atomic per wave) instead of 32 ballot/leader-atomic chains per thread.
// Degree now derives from cnt + diag_nz (no separate count reduce).
// ---------------------------------------------------------------------------
__global__ __launch_bounds__(256) void mega_build_gemm1(
    const float* __restrict__ adj, const float* __restrict__ x,
    const float* __restrict__ W1, int* __restrict__ cols,
    int* __restrict__ rowcount, float* __restrict__ dinv,
    float* __restrict__ diagv, float* __restrict__ XW1) {
  __shared__ __align__(16) unsigned short sAh[64][40];
  __shared__ __align__(16) unsigned short sAl[64][40];
  __shared__ __align__(16) unsigned short sBh[64][40];
  __shared__ __align__(16) unsigned short sBl[64][40];
  __shared__ int cnt;
  __shared__ int diag_nz;

  int t = threadIdx.x;
  int lane = t & 63;

  if (blockIdx.x < 512) {
    // ===================== GEMM1 path (64x64 tile) =====================
    const int K = 512;
    int b = blockIdx.x;
    int bn = (b & 3) * 64;
    int bm = (b >> 2) * 64;
    int w = t >> 6;  // wave owns rows w*16..w*16+15 of the tile
    int quad = lane >> 4, m16 = lane & 15;
    f32x4 acc[4] = {};
    for (int k0 = 0; k0 < K; k0 += 32) {
#pragma unroll
      for (int i = 0; i < 2; i++) {  // A tile: 64 rows x 32 k
        int id = t + i * 256;
        int row = id >> 3;
        int fq = id & 7;
        float4 v = *(const float4*)&x[(size_t)(bm + row) * K + k0 + fq * 4];
        ushort4 h, l;
        h.x = f2bf(v.x); l.x = f2bf(v.x - bf2f(h.x));
        h.y = f2bf(v.y); l.y = f2bf(v.y - bf2f(h.y));
        h.z = f2bf(v.z); l.z = f2bf(v.z - bf2f(h.z));
        h.w = f2bf(v.w); l.w = f2bf(v.w - bf2f(h.w));
        *(ushort4*)&sAh[row][fq * 4] = h;
        *(ushort4*)&sAl[row][fq * 4] = l;
      }
#pragma unroll
      for (int j = 0; j < 2; j++) {  // B tile: 64 n x 32 k
        int id = t + j * 256;
        int k = id >> 4;
        int n4 = (id & 15) * 4;
        float4 v = *(const float4*)&W1[(size_t)(k0 + k) * 256 + bn + n4];
        float va[4] = {v.x, v.y, v.z, v.w};
#pragma unroll
        for (int c = 0; c < 4; c++) {
          unsigned short h = f2bf(va[c]);
          sBh[n4 + c][k] = h;
          sBl[n4 + c][k] = f2bf(va[c] - bf2f(h));
        }
      }
      __syncthreads();
      short8 ah = *(const short8*)&sAh[w * 16 + m16][quad * 8];
      short8 al = *(const short8*)&sAl[w * 16 + m16][quad * 8];
#pragma unroll
      for (int j = 0; j < 4; j++) {
        short8 bh = *(const short8*)&sBh[j * 16 + m16][quad * 8];
        short8 bl = *(const short8*)&sBl[j * 16 + m16][quad * 8];
        acc[j] = __builtin_amdgcn_mfma_f32_16x16x32_bf16(ah, bh, acc[j], 0, 0, 0);
        acc[j] = __builtin_amdgcn_mfma_f32_16x16x32_bf16(al, bh, acc[j], 0, 0, 0);
        acc[j] = __builtin_amdgcn_mfma_f32_16x16x32_bf16(ah, bl, acc[j], 0, 0, 0);
      }
      __syncthreads();
    }
#pragma unroll
    for (int j = 0; j < 4; j++)
#pragma unroll
      for (int r = 0; r < 4; r++)
        XW1[(size_t)(bm + w * 16 + quad * 4 + r) * 256 + bn + j * 16 + m16] =
            acc[j][r];
  } else {
    // ===================== build_graph path =====================
    int row = blockIdx.x - 512;
    if (t == 0) { cnt = 0; diag_nz = 0; }
    __syncthreads();
    const float4* arow = (const float4*)(adj + (size_t)row * NV);
    // Batch the whole 32 KB row: 8 independent float4 loads in flight per
    // thread BEFORE any dependent work.
    float4 vv[8];
    vv[0] = arow[t + 0 * 256];
    vv[1] = arow[t + 1 * 256];
    vv[2] = arow[t + 2 * 256];
    vv[3] = arow[t + 3 * 256];
    vv[4] = arow[t + 4 * 256];
    vv[5] = arow[t + 5 * 256];
    vv[6] = arow[t + 6 * 256];
    vv[7] = arow[t + 7 * 256];
    // Per-thread nz bitmask over the 32 scalar elements (bit p = u*4+j,
    // column c = 4t + 1024u + j). Diagonal handled separately.
    unsigned int wm = 0;
#pragma unroll
    for (int u = 0; u < 8; u++) {
      float va[4] = {vv[u].x, vv[u].y, vv[u].z, vv[u].w};
#pragma unroll
      for (int j = 0; j < 4; j++) {
        bool nz = (va[j] != 0.0f);
        int c = 4 * t + (u << 10) + j;
        if (nz) {
          if (c == row) diag_nz = 1;  // benign shared race (all write 1)
          else wm |= 1u << (u * 4 + j);
        }
      }
    }
    int myc = __popc(wm);
    // Wave-inclusive prefix scan of myc (6-step Hillis-Steele).
    int pre = myc;
#pragma unroll
    for (int off = 1; off < 64; off <<= 1) {
      int nb = __shfl_up(pre, off, 64);
      if (lane >= off) pre += nb;
    }
    int wtot = __shfl(pre, 63, 64);  // wave total
    int base = 0;
    if (lane == 63) base = atomicAdd(&cnt, wtot);
    base = __shfl(base, 63, 64);
    int p0 = base + (pre - myc);  // exclusive prefix + wave base
    while (wm) {
      int p = __ffs(wm) - 1;
      wm &= wm - 1;
      int c = 4 * t + ((p >> 2) << 10) + (p & 3);
      if (p0 < CAP) cols[(size_t)row * CAP + p0] = c;
      p0++;
    }
    __syncthreads();
    if (t == 0) {
      // total nz of adj row = off-diag written (cnt) + diag flag
      float deg = (float)(cnt + diag_nz) + 1.0f;  // A_hat adds eye
      dinv[row] = 1.0f / sqrtf(deg);
      diagv[row] = diag_nz ? 2.0f : 1.0f;
      rowcount[row] = cnt > CAP ? CAP : cnt;
    }
  }
}

// ---------------------------------------------------------------------------
// Kernel C: layer-1 aggregate + relu. One WAVE per row, float4 per lane,
// unroll x8 -> 8 independent 1 KB gathers in flight; 4x and scalar tails.
// ---------------------------------------------------------------------------
__global__ __launch_bounds__(256) void spmm_relu_k(
    const float* __restrict__ Z, const int* __restrict__ cols,
    const int* __restrict__ rowcount, const float* __restrict__ dinv,
    const float* __restrict__ diagv, float* __restrict__ H) {
  int lane = threadIdx.x & 63;
  int row = blockIdx.x * 4 + (threadIdx.x >> 6);
  const float4* Zr = (const float4*)Z;
  float di = dinv[row];
  float4 z = Zr[(size_t)row * 64 + lane];
  float dd = diagv[row] * di;
  float4 acc;
  acc.x = dd * z.x; acc.y = dd * z.y; acc.z = dd * z.z; acc.w = dd * z.w;
  int cnt = rowcount[row];
  const int* cr = cols + (size_t)row * CAP;
  int e = 0;
  for (; e + 8 <= cnt; e += 8) {
    int c0 = cr[e + 0], c1 = cr[e + 1], c2 = cr[e + 2], c3 = cr[e + 3];
    int c4 = cr[e + 4], c5 = cr[e + 5], c6 = cr[e + 6], c7 = cr[e + 7];
    float w0 = dinv[c0], w1 = dinv[c1], w2 = dinv[c2], w3 = dinv[c3];
    float w4 = dinv[c4], w5 = dinv[c5], w6 = dinv[c6], w7 = dinv[c7];
    float4 g0 = Zr[(size_t)c0 * 64 + lane];
    float4 g1 = Zr[(size_t)c1 * 64 + lane];
    float4 g2 = Zr[(size_t)c2 * 64 + lane];
    float4 g3 = Zr[(size_t)c3 * 64 + lane];
    float4 g4 = Zr[(size_t)c4 * 64 + lane];
    float4 g5 = Zr[(size_t)c5 * 64 + lane];
    float4 g6 = Zr[(size_t)c6 * 64 + lane];
    float4 g7 = Zr[(size_t)c7 * 64 + lane];
    acc.x += w0 * g0.x + w1 * g1.x + w2 * g2.x + w3 * g3.x;
    acc.y += w0 * g0.y + w1 * g1.y + w2 * g2.y + w3 * g3.y;
    acc.z += w0 * g0.z + w1 * g1.z + w2 * g2.z + w3 * g3.z;
    acc.w += w0 * g0.w + w1 * g1.w + w2 * g2.w + w3 * g3.w;
    acc.x += w4 * g4.x + w5 * g5.x + w6 * g6.x + w7 * g7.x;
    acc.y += w4 * g4.y + w5 * g5.y + w6 * g6.y + w7 * g7.y;
    acc.z += w4 * g4.z + w5 * g5.z + w6 * g6.z + w7 * g7.z;
    acc.w += w4 * g4.w + w5 * g5.w + w6 * g6.w + w7 * g7.w;
  }
  for (; e + 4 <= cnt; e += 4) {
    int c0 = cr[e + 0], c1 = cr[e + 1], c2 = cr[e + 2], c3 = cr[e + 3];
    float w0 = dinv[c0], w1 = dinv[c1], w2 = dinv[c2], w3 = dinv[c3];
    float4 g0 = Zr[(size_t)c0 * 64 + lane];
    float4 g1 = Zr[(size_t)c1 * 64 + lane];
    float4 g2 = Zr[(size_t)c2 * 64 + lane];
    float4 g3 = Zr[(size_t)c3 * 64 + lane];
    acc.x += w0 * g0.x + w1 * g1.x + w2 * g2.x + w3 * g3.x;
    acc.y += w0 * g0.y + w1 * g1.y + w2 * g2.y + w3 * g3.y;
    acc.z += w0 * g0.z + w1 * g1.z + w2 * g2.z + w3 * g3.z;
    acc.w += w0 * g0.w + w1 * g1.w + w2 * g2.w + w3 * g3.w;
  }
  for (; e < cnt; e++) {
    int c = cr[e];
    float w = dinv[c];
    float4 g = Zr[(size_t)c * 64 + lane];
    acc.x += w * g.x; acc.y += w * g.y; acc.z += w * g.z; acc.w += w * g.w;
  }
  float4 o;
  o.x = fmaxf(acc.x * di, 0.0f);
  o.y = fmaxf(acc.y * di, 0.0f);
  o.z = fmaxf(acc.z * di, 0.0f);
  o.w = fmaxf(acc.w * di, 0.0f);
  ((float4*)H)[(size_t)row * 64 + lane] = o;
}

// ---------------------------------------------------------------------------
// Kernel D: layer-2 GEMM via split-bf16 MFMA. HW2[8192][64] = H @ W2 with
// cols 40..63 exact zeros (B staged as zero there). 256 blocks x 32-row
// tiles. Wave w: m-half = w&1 (16 rows), n-pair = (w>>1)*2. LDS ~15.4 KB.
// ---------------------------------------------------------------------------
__global__ __launch_bounds__(256) void gemm2_mfma(
    const float* __restrict__ H, const float* __restrict__ W2,
    float* __restrict__ HW2) {
  const int K = 256;
  __shared__ __align__(16) unsigned short sAh[32][40];
  __shared__ __align__(16) unsigned short sAl[32][40];
  __shared__ __align__(16) unsigned short sBh[64][40];
  __shared__ __align__(16) unsigned short sBl[64][40];
  int t = threadIdx.x;
  int bm = blockIdx.x * 32;
  int lane = t & 63, w = t >> 6;
  int quad = lane >> 4, m16 = lane & 15;
  int i = w & 1;          // m-half
  int jj = (w >> 1) * 2;  // first n-frag
  f32x4 acc[2] = {};
  for (int k0 = 0; k0 < K; k0 += 32) {
    {  // A tile: 32 rows x 32 k from H (f32), inline hi/lo split
      int row = t >> 3;        // 0..31
      int fq = t & 7;          // k = fq*4
      float4 v = *(const float4*)&H[(size_t)(bm + row) * K + k0 + fq * 4];
      ushort4 h, l;
      h.x = f2bf(v.x); l.x = f2bf(v.x - bf2f(h.x));
      h.y = f2bf(v.y); l.y = f2bf(v.y - bf2f(h.y));
      h.z = f2bf(v.z); l.z = f2bf(v.z - bf2f(h.z));
      h.w = f2bf(v.w); l.w = f2bf(v.w - bf2f(h.w));
      *(ushort4*)&sAh[row][fq * 4] = h;
      *(ushort4*)&sAl[row][fq * 4] = l;
    }
#pragma unroll
    for (int j = 0; j < 2; j++) {  // B tile: 64 n x 32 k from W2[k][n<40]
      int id = t + j * 256;        // 0..511
      int k = id >> 4;             // 0..31
      int n4 = (id & 15) * 4;      // 0..60
#pragma unroll
      for (int c = 0; c < 4; c++) {
        float v = (n4 + c < 40) ? W2[(size_t)(k0 + k) * 40 + n4 + c] : 0.0f;
        unsigned short h = f2bf(v);
        sBh[n4 + c][k] = h;
        sBl[n4 + c][k] = f2bf(v - bf2f(h));
      }
    }
    __syncthreads();
    short8 ah = *(const short8*)&sAh[i * 16 + m16][quad * 8];
    short8 al = *(const short8*)&sAl[i * 16 + m16][quad * 8];
#pragma unroll
    for (int jx = 0; jx < 2; jx++) {
      short8 bh = *(const short8*)&sBh[(jj + jx) * 16 + m16][quad * 8];
      short8 bl = *(const short8*)&sBl[(jj + jx) * 16 + m16][quad * 8];
      acc[jx] = __builtin_amdgcn_mfma_f32_16x16x32_bf16(ah, bh, acc[jx], 0, 0, 0);
      acc[jx] = __builtin_amdgcn_mfma_f32_16x16x32_bf16(al, bh, acc[jx], 0, 0, 0);
      acc[jx] = __builtin_amdgcn_mfma_f32_16x16x32_bf16(ah, bl, acc[jx], 0, 0, 0);
    }
    __syncthreads();
  }
#pragma unroll
  for (int jx = 0; jx < 2; jx++)
#pragma unroll
    for (int r = 0; r < 4; r++)
      HW2[(size_t)(bm + i * 16 + quad * 4 + r) * 64 + (jj + jx) * 16 + m16] =
          acc[jx][r];
}

// ---------------------------------------------------------------------------
// Kernel E: layer-2 aggregate + relu + log_softmax (wave per row, 64-wide
// padded HW2; cols 40..63 exact zeros from gemm2_mfma). Unroll x8 gathers.
// ---------------------------------------------------------------------------
__global__ __launch_bounds__(256) void spmm2_lsm_k(
    const float* __restrict__ Z, const int* __restrict__ cols,
    const int* __restrict__ rowcount, const float* __restrict__ dinv,
    const float* __restrict__ diagv, float* __restrict__ out) {
  int lane = threadIdx.x & 63;
  int row = blockIdx.x * 4 + (threadIdx.x >> 6);
  float di = dinv[row];
  float acc = diagv[row] * di * Z[(size_t)row * 64 + lane];
  int cnt = rowcount[row];
  const int* cr = cols + (size_t)row * CAP;
  int e = 0;
  for (; e + 8 <= cnt; e += 8) {
    int c0 = cr[e + 0], c1 = cr[e + 1], c2 = cr[e + 2], c3 = cr[e + 3];
    int c4 = cr[e + 4], c5 = cr[e + 5], c6 = cr[e + 6], c7 = cr[e + 7];
    float w0 = dinv[c0], w1 = dinv[c1], w2 = dinv[c2], w3 = dinv[c3];
    float w4 = dinv[c4], w5 = dinv[c5], w6 = dinv[c6], w7 = dinv[c7];
    float g0 = Z[(size_t)c0 * 64 + lane];
    float g1 = Z[(size_t)c1 * 64 + lane];
    float g2 = Z[(size_t)c2 * 64 + lane];
    float g3 = Z[(size_t)c3 * 64 + lane];
    float g4 = Z[(size_t)c4 * 64 + lane];
    float g5 = Z[(size_t)c5 * 64 + lane];
    float g6 = Z[(size_t)c6 * 64 + lane];
    float g7 = Z[(size_t)c7 * 64 + lane];
    acc += w0 * g0 + w1 * g1 + w2 * g2 + w3 * g3;
    acc += w4 * g4 + w5 * g5 + w6 * g6 + w7 * g7;
  }
  for (; e + 4 <= cnt; e += 4) {
    int c0 = cr[e + 0], c1 = cr[e + 1], c2 = cr[e + 2], c3 = cr[e + 3];
    float w0 = dinv[c0], w1 = dinv[c1], w2 = dinv[c2], w3 = dinv[c3];
    acc += w0 * Z[(size_t)c0 * 64 + lane] + w1 * Z[(size_t)c1 * 64 + lane] +
           w2 * Z[(size_t)c2 * 64 + lane] + w3 * Z[(size_t)c3 * 64 + lane];
  }
  for (; e < cnt; e++) {
    int c = cr[e];
    acc += dinv[c] * Z[(size_t)c * 64 + lane];
  }
  float h2 = (lane < 40) ? fmaxf(acc * di, 0.0f) : -INFINITY;
  float m = h2;
  for (int off = 32; off > 0; off >>= 1) m = fmaxf(m, __shfl_xor(m, off, 64));
  float ex = (lane < 40) ? expf(h2 - m) : 0.0f;
  float s = ex;
  for (int off = 32; off > 0; off >>= 1) s += __shfl_xor(s, off, 64);
  float ls = logf(s);
  if (lane < 40) out[(size_t)row * 40 + lane] = h2 - m - ls;
}

// ---------------------------------------------------------------------------
// Workspace (bytes, 16B-aligned):
//   cols @ 0 : 2097152        rowcount @ 2097152 : 32768
//   dinv @ 2129920 : 32768    diagv    @ 2162688 : 32768
//   XW1  @ 2195456 : 8388608  H        @ 10584064 : 8388608
//   HW2  @ 18972672 : 2097152 (8192 x 64, cols 40..63 zero)
// ---------------------------------------------------------------------------
extern "C" void kernel_launch(void* const* d_in, const int* in_sizes, int n_in,
                              void* d_out, int out_size, void* d_ws, size_t ws_size,
                              hipStream_t stream) {
  (void)in_sizes; (void)n_in; (void)out_size; (void)ws_size;
  const float* x   = (const float*)d_in[0];
  const float* adj = (const float*)d_in[1];
  const float* W1  = (const float*)d_in[2];
  const float* W2  = (const float*)d_in[3];
  float* out = (float*)d_out;
  char* ws = (char*)d_ws;

  int*   cols     = (int*)(ws);
  int*   rowcount = (int*)(ws + 2097152);
  float* dinv     = (float*)(ws + 2129920);
  float* diagv    = (float*)(ws + 2162688);
  float* XW1      = (float*)(ws + 2195456);
  float* H        = (float*)(ws + 10584064);
  float* HW2      = (float*)(ws + 18972672);

  hipLaunchKernelGGL(mega_build_gemm1, dim3(512 + NV), dim3(256), 0, stream,
                     adj, x, W1, cols, rowcount, dinv, diagv, XW1);
  hipLaunchKernelGGL(spmm_relu_k, dim3(NV / 4), dim3(256), 0, stream,
                     XW1, cols, rowcount, dinv, diagv, H);
  hipLaunchKernelGGL(gemm2_mfma, dim3(NV / 32), dim3(256), 0, stream,
                     H, W2, HW2);
  hipLaunchKernelGGL(spmm2_lsm_k, dim3(NV / 4), dim3(256), 0, stream,
                     HW2, cols, rowcount, dinv, diagv, out);
}

// Round 3
// 399.438 us; speedup vs baseline: 1.0775x; 1.0201x over previous
//
#include <hip/hip_runtime.h>
#include <math.h>

#define NV 8192
#define CAP 64

typedef __attribute__((ext_vector_type(8))) short short8;
typedef __attribute__((ext_vector_type(4))) float f32x4;

static __device__ __forceinline__ unsigned short f2bf(float v) {
  unsigned int u = __float_as_uint(v);
  unsigned int r = (u + 0x7fffu + ((u >> 16) & 1u)) >> 16;  // RNE
  return (unsigned short)r;
}
static __device__ __forceinline__ float bf2f(unsigned short h) {
  return __uint_as_float(((unsigned int)h) << 16);
}

// ---------------------------------------------------------------------------
// MEGA kernel: blocks 0..511 = GEMM1 (XW1 = x @ W1, split-bf16 MFMA, 64x64
// tiles, LDS 20.5 KB -> 7 blocks/CU); blocks 512..8703 = build_graph
// (batched 32 KB row read + scan-based compaction). [40] inner dim kept:
// stride 80 B preserves 16-B alignment for ds_read_b128 fragment loads.
// ---------------------------------------------------------------------------
__global__ __launch_bounds__(256) void mega_build_gemm1(
    const float* __restrict__ adj, const float* __restrict__ x,
    const float* __restrict__ W1, int* __restrict__ cols,
    int* __restrict__ rowcount, float* __restrict__ dinv,
    float* __restrict__ diagv, float* __restrict__ XW1) {
  __shared__ __align__(16) unsigned short sAh[64][40];
  __shared__ __align__(16) unsigned short sAl[64][40];
  __shared__ __align__(16) unsigned short sBh[64][40];
  __shared__ __align__(16) unsigned short sBl[64][40];
  __shared__ int cnt;
  __shared__ int diag_nz;

  int t = threadIdx.x;
  int lane = t & 63;

  if (blockIdx.x < 512) {
    // ===================== GEMM1 path (64x64 tile) =====================
    const int K = 512;
    int b = blockIdx.x;
    int bn = (b & 3) * 64;
    int bm = (b >> 2) * 64;
    int w = t >> 6;  // wave owns rows w*16..w*16+15 of the tile
    int quad = lane >> 4, m16 = lane & 15;
    f32x4 acc[4] = {};
    for (int k0 = 0; k0 < K; k0 += 32) {
#pragma unroll
      for (int i = 0; i < 2; i++) {  // A tile: 64 rows x 32 k
        int id = t + i * 256;
        int row = id >> 3;
        int fq = id & 7;
        float4 v = *(const float4*)&x[(size_t)(bm + row) * K + k0 + fq * 4];
        ushort4 h, l;
        h.x = f2bf(v.x); l.x = f2bf(v.x - bf2f(h.x));
        h.y = f2bf(v.y); l.y = f2bf(v.y - bf2f(h.y));
        h.z = f2bf(v.z); l.z = f2bf(v.z - bf2f(h.z));
        h.w = f2bf(v.w); l.w = f2bf(v.w - bf2f(h.w));
        *(ushort4*)&sAh[row][fq * 4] = h;
        *(ushort4*)&sAl[row][fq * 4] = l;
      }
#pragma unroll
      for (int j = 0; j < 2; j++) {  // B tile: 64 n x 32 k
        int id = t + j * 256;
        int k = id >> 4;
        int n4 = (id & 15) * 4;
        float4 v = *(const float4*)&W1[(size_t)(k0 + k) * 256 + bn + n4];
        float va[4] = {v.x, v.y, v.z, v.w};
#pragma unroll
        for (int c = 0; c < 4; c++) {
          unsigned short h = f2bf(va[c]);
          sBh[n4 + c][k] = h;
          sBl[n4 + c][k] = f2bf(va[c] - bf2f(h));
        }
      }
      __syncthreads();
      short8 ah = *(const short8*)&sAh[w * 16 + m16][quad * 8];
      short8 al = *(const short8*)&sAl[w * 16 + m16][quad * 8];
#pragma unroll
      for (int j = 0; j < 4; j++) {
        short8 bh = *(const short8*)&sBh[j * 16 + m16][quad * 8];
        short8 bl = *(const short8*)&sBl[j * 16 + m16][quad * 8];
        acc[j] = __builtin_amdgcn_mfma_f32_16x16x32_bf16(ah, bh, acc[j], 0, 0, 0);
        acc[j] = __builtin_amdgcn_mfma_f32_16x16x32_bf16(al, bh, acc[j], 0, 0, 0);
        acc[j] = __builtin_amdgcn_mfma_f32_16x16x32_bf16(ah, bl, acc[j], 0, 0, 0);
      }
      __syncthreads();
    }
#pragma unroll
    for (int j = 0; j < 4; j++)
#pragma unroll
      for (int r = 0; r < 4; r++)
        XW1[(size_t)(bm + w * 16 + quad * 4 + r) * 256 + bn + j * 16 + m16] =
            acc[j][r];
  } else {
    // ===================== build_graph path =====================
    int row = blockIdx.x - 512;
    if (t == 0) { cnt = 0; diag_nz = 0; }
    __syncthreads();
    const float4* arow = (const float4*)(adj + (size_t)row * NV);
    float4 vv[8];
    vv[0] = arow[t + 0 * 256];
    vv[1] = arow[t + 1 * 256];
    vv[2] = arow[t + 2 * 256];
    vv[3] = arow[t + 3 * 256];
    vv[4] = arow[t + 4 * 256];
    vv[5] = arow[t + 5 * 256];
    vv[6] = arow[t + 6 * 256];
    vv[7] = arow[t + 7 * 256];
    unsigned int wm = 0;
#pragma unroll
    for (int u = 0; u < 8; u++) {
      float va[4] = {vv[u].x, vv[u].y, vv[u].z, vv[u].w};
#pragma unroll
      for (int j = 0; j < 4; j++) {
        bool nz = (va[j] != 0.0f);
        int c = 4 * t + (u << 10) + j;
        if (nz) {
          if (c == row) diag_nz = 1;  // benign shared race (all write 1)
          else wm |= 1u << (u * 4 + j);
        }
      }
    }
    int myc = __popc(wm);
    int pre = myc;
#pragma unroll
    for (int off = 1; off < 64; off <<= 1) {
      int nb = __shfl_up(pre, off, 64);
      if (lane >= off) pre += nb;
    }
    int wtot = __shfl(pre, 63, 64);
    int base = 0;
    if (lane == 63) base = atomicAdd(&cnt, wtot);
    base = __shfl(base, 63, 64);
    int p0 = base + (pre - myc);
    while (wm) {
      int p = __ffs(wm) - 1;
      wm &= wm - 1;
      int c = 4 * t + ((p >> 2) << 10) + (p & 3);
      if (p0 < CAP) cols[(size_t)row * CAP + p0] = c;
      p0++;
    }
    __syncthreads();
    if (t == 0) {
      float deg = (float)(cnt + diag_nz) + 1.0f;  // A_hat adds eye
      dinv[row] = 1.0f / sqrtf(deg);
      diagv[row] = diag_nz ? 2.0f : 1.0f;
      rowcount[row] = cnt > CAP ? CAP : cnt;
    }
  }
}

// ---------------------------------------------------------------------------
// FUSED middle kernel: layer-1 aggregate+relu AND layer-2 GEMM in one launch.
// 256 blocks x 512 threads; block owns rows [bm, bm+32).
// Phase A: wave-per-row gather of A_norm @ XW1 (8-deep batched), relu, park
//   H-tile in LDS sH[32][260] (f32; +4 pad keeps b128 reads 16B-aligned and
//   spreads banks; stride 1040 B).
// Phase B: 32x64 GEMM2 tile straight from LDS. A-fragments: 2x ds_read_b128
//   + in-reg hi/lo bf16 split. B-fragments: per-lane scalar loads from W2
//   (40 KB, L2-resident) -> NO B staging, NO barriers inside the K-loop.
// Removes: spmm->gemm2 launch gap + the 16.8 MB H global round-trip.
// ---------------------------------------------------------------------------
__global__ __launch_bounds__(512) void spmm1_gemm2_k(
    const float* __restrict__ XW1, const int* __restrict__ cols,
    const int* __restrict__ rowcount, const float* __restrict__ dinv,
    const float* __restrict__ diagv, const float* __restrict__ W2,
    float* __restrict__ HW2) {
  __shared__ __align__(16) float sH[32][260];
  int t = threadIdx.x;
  int lane = t & 63;
  int w = t >> 6;  // 0..7
  int bm = blockIdx.x * 32;
  const float4* Zr = (const float4*)XW1;

  // ---------------- Phase A: aggregate 32 rows ----------------
#pragma unroll
  for (int pass = 0; pass < 4; pass++) {
    int r = pass * 8 + w;  // local row 0..31
    int row = bm + r;
    float di = dinv[row];
    float4 z = Zr[(size_t)row * 64 + lane];
    float dd = diagv[row] * di;
    float4 acc;
    acc.x = dd * z.x; acc.y = dd * z.y; acc.z = dd * z.z; acc.w = dd * z.w;
    int cnt = rowcount[row];
    const int* cr = cols + (size_t)row * CAP;
    int e = 0;
    for (; e + 8 <= cnt; e += 8) {
      int c0 = cr[e + 0], c1 = cr[e + 1], c2 = cr[e + 2], c3 = cr[e + 3];
      int c4 = cr[e + 4], c5 = cr[e + 5], c6 = cr[e + 6], c7 = cr[e + 7];
      float w0 = dinv[c0], w1 = dinv[c1], w2 = dinv[c2], w3 = dinv[c3];
      float w4 = dinv[c4], w5 = dinv[c5], w6 = dinv[c6], w7 = dinv[c7];
      float4 g0 = Zr[(size_t)c0 * 64 + lane];
      float4 g1 = Zr[(size_t)c1 * 64 + lane];
      float4 g2 = Zr[(size_t)c2 * 64 + lane];
      float4 g3 = Zr[(size_t)c3 * 64 + lane];
      float4 g4 = Zr[(size_t)c4 * 64 + lane];
      float4 g5 = Zr[(size_t)c5 * 64 + lane];
      float4 g6 = Zr[(size_t)c6 * 64 + lane];
      float4 g7 = Zr[(size_t)c7 * 64 + lane];
      acc.x += w0 * g0.x + w1 * g1.x + w2 * g2.x + w3 * g3.x;
      acc.y += w0 * g0.y + w1 * g1.y + w2 * g2.y + w3 * g3.y;
      acc.z += w0 * g0.z + w1 * g1.z + w2 * g2.z + w3 * g3.z;
      acc.w += w0 * g0.w + w1 * g1.w + w2 * g2.w + w3 * g3.w;
      acc.x += w4 * g4.x + w5 * g5.x + w6 * g6.x + w7 * g7.x;
      acc.y += w4 * g4.y + w5 * g5.y + w6 * g6.y + w7 * g7.y;
      acc.z += w4 * g4.z + w5 * g5.z + w6 * g6.z + w7 * g7.z;
      acc.w += w4 * g4.w + w5 * g5.w + w6 * g6.w + w7 * g7.w;
    }
    for (; e + 4 <= cnt; e += 4) {
      int c0 = cr[e + 0], c1 = cr[e + 1], c2 = cr[e + 2], c3 = cr[e + 3];
      float w0 = dinv[c0], w1 = dinv[c1], w2 = dinv[c2], w3 = dinv[c3];
      float4 g0 = Zr[(size_t)c0 * 64 + lane];
      float4 g1 = Zr[(size_t)c1 * 64 + lane];
      float4 g2 = Zr[(size_t)c2 * 64 + lane];
      float4 g3 = Zr[(size_t)c3 * 64 + lane];
      acc.x += w0 * g0.x + w1 * g1.x + w2 * g2.x + w3 * g3.x;
      acc.y += w0 * g0.y + w1 * g1.y + w2 * g2.y + w3 * g3.y;
      acc.z += w0 * g0.z + w1 * g1.z + w2 * g2.z + w3 * g3.z;
      acc.w += w0 * g0.w + w1 * g1.w + w2 * g2.w + w3 * g3.w;
    }
    for (; e < cnt; e++) {
      int c = cr[e];
      float ww = dinv[c];
      float4 g = Zr[(size_t)c * 64 + lane];
      acc.x += ww * g.x; acc.y += ww * g.y; acc.z += ww * g.z; acc.w += ww * g.w;
    }
    float4 o;
    o.x = fmaxf(acc.x * di, 0.0f);
    o.y = fmaxf(acc.y * di, 0.0f);
    o.z = fmaxf(acc.z * di, 0.0f);
    o.w = fmaxf(acc.w * di, 0.0f);
    *(float4*)&sH[r][lane * 4] = o;
  }
  __syncthreads();

  // ---------------- Phase B: 32x64 GEMM2 from LDS ----------------
  int quad = lane >> 4, m16 = lane & 15;
  int i = w & 1;   // m-half (16 rows)
  int j = w >> 1;  // n-frag 0..3 (16 cols)
  int n = j * 16 + m16;
  int rl = i * 16 + m16;
  f32x4 acc2 = {};
  for (int k0 = 0; k0 < 256; k0 += 32) {
    // B fragment: 8 scalar W2 loads (stride 160 B, L2-resident), zero n>=40
    short8 bh = {}, bl = {};
    if (n < 40) {
#pragma unroll
      for (int e2 = 0; e2 < 8; e2++) {
        float v = W2[(size_t)(k0 + quad * 8 + e2) * 40 + n];
        unsigned short h = f2bf(v);
        bh[e2] = (short)h;
        bl[e2] = (short)f2bf(v - bf2f(h));
      }
    }
    // A fragment: 8 consecutive f32 from LDS, split hi/lo in regs
    float4 a0 = *(const float4*)&sH[rl][k0 + quad * 8];
    float4 a1 = *(const float4*)&sH[rl][k0 + quad * 8 + 4];
    float af[8] = {a0.x, a0.y, a0.z, a0.w, a1.x, a1.y, a1.z, a1.w};
    short8 ah, al;
#pragma unroll
    for (int e2 = 0; e2 < 8; e2++) {
      unsigned short h = f2bf(af[e2]);
      ah[e2] = (short)h;
      al[e2] = (short)f2bf(af[e2] - bf2f(h));
    }
    acc2 = __builtin_amdgcn_mfma_f32_16x16x32_bf16(ah, bh, acc2, 0, 0, 0);
    acc2 = __builtin_amdgcn_mfma_f32_16x16x32_bf16(al, bh, acc2, 0, 0, 0);
    acc2 = __builtin_amdgcn_mfma_f32_16x16x32_bf16(ah, bl, acc2, 0, 0, 0);
  }
#pragma unroll
  for (int r = 0; r < 4; r++)
    HW2[(size_t)(bm + i * 16 + quad * 4 + r) * 64 + n] = acc2[r];
}

// ---------------------------------------------------------------------------
// Kernel E: layer-2 aggregate + relu + log_softmax (wave per row, 64-wide
// padded HW2; cols 40..63 exact zeros). Unroll x8 gathers.
// ---------------------------------------------------------------------------
__global__ __launch_bounds__(256) void spmm2_lsm_k(
    const float* __restrict__ Z, const int* __restrict__ cols,
    const int* __restrict__ rowcount, const float* __restrict__ dinv,
    const float* __restrict__ diagv, float* __restrict__ out) {
  int lane = threadIdx.x & 63;
  int row = blockIdx.x * 4 + (threadIdx.x >> 6);
  float di = dinv[row];
  float acc = diagv[row] * di * Z[(size_t)row * 64 + lane];
  int cnt = rowcount[row];
  const int* cr = cols + (size_t)row * CAP;
  int e = 0;
  for (; e + 8 <= cnt; e += 8) {
    int c0 = cr[e + 0], c1 = cr[e + 1], c2 = cr[e + 2], c3 = cr[e + 3];
    int c4 = cr[e + 4], c5 = cr[e + 5], c6 = cr[e + 6], c7 = cr[e + 7];
    float w0 = dinv[c0], w1 = dinv[c1], w2 = dinv[c2], w3 = dinv[c3];
    float w4 = dinv[c4], w5 = dinv[c5], w6 = dinv[c6], w7 = dinv[c7];
    float g0 = Z[(size_t)c0 * 64 + lane];
    float g1 = Z[(size_t)c1 * 64 + lane];
    float g2 = Z[(size_t)c2 * 64 + lane];
    float g3 = Z[(size_t)c3 * 64 + lane];
    float g4 = Z[(size_t)c4 * 64 + lane];
    float g5 = Z[(size_t)c5 * 64 + lane];
    float g6 = Z[(size_t)c6 * 64 + lane];
    float g7 = Z[(size_t)c7 * 64 + lane];
    acc += w0 * g0 + w1 * g1 + w2 * g2 + w3 * g3;
    acc += w4 * g4 + w5 * g5 + w6 * g6 + w7 * g7;
  }
  for (; e + 4 <= cnt; e += 4) {
    int c0 = cr[e + 0], c1 = cr[e + 1], c2 = cr[e + 2], c3 = cr[e + 3];
    float w0 = dinv[c0], w1 = dinv[c1], w2 = dinv[c2], w3 = dinv[c3];
    acc += w0 * Z[(size_t)c0 * 64 + lane] + w1 * Z[(size_t)c1 * 64 + lane] +
           w2 * Z[(size_t)c2 * 64 + lane] + w3 * Z[(size_t)c3 * 64 + lane];
  }
  for (; e < cnt; e++) {
    int c = cr[e];
    acc += dinv[c] * Z[(size_t)c * 64 + lane];
  }
  float h2 = (lane < 40) ? fmaxf(acc * di, 0.0f) : -INFINITY;
  float m = h2;
  for (int off = 32; off > 0; off >>= 1) m = fmaxf(m, __shfl_xor(m, off, 64));
  float ex = (lane < 40) ? expf(h2 - m) : 0.0f;
  float s = ex;
  for (int off = 32; off > 0; off >>= 1) s += __shfl_xor(s, off, 64);
  float ls = logf(s);
  if (lane < 40) out[(size_t)row * 40 + lane] = h2 - m - ls;
}

// ---------------------------------------------------------------------------
// Workspace (bytes, 16B-aligned):
//   cols @ 0 : 2097152        rowcount @ 2097152 : 32768
//   dinv @ 2129920 : 32768    diagv    @ 2162688 : 32768
//   XW1  @ 2195456 : 8388608  HW2      @ 10584064 : 2097152
//   (H eliminated: layer-1 output lives in LDS of the fused kernel)
// ---------------------------------------------------------------------------
extern "C" void kernel_launch(void* const* d_in, const int* in_sizes, int n_in,
                              void* d_out, int out_size, void* d_ws, size_t ws_size,
                              hipStream_t stream) {
  (void)in_sizes; (void)n_in; (void)out_size; (void)ws_size;
  const float* x   = (const float*)d_in[0];
  const float* adj = (const float*)d_in[1];
  const float* W1  = (const float*)d_in[2];
  const float* W2  = (const float*)d_in[3];
  float* out = (float*)d_out;
  char* ws = (char*)d_ws;

  int*   cols     = (int*)(ws);
  int*   rowcount = (int*)(ws + 2097152);
  float* dinv     = (float*)(ws + 2129920);
  float* diagv    = (float*)(ws + 2162688);
  float* XW1      = (float*)(ws + 2195456);
  float* HW2      = (float*)(ws + 10584064);

  hipLaunchKernelGGL(mega_build_gemm1, dim3(512 + NV), dim3(256), 0, stream,
                     adj, x, W1, cols, rowcount, dinv, diagv, XW1);
  hipLaunchKernelGGL(spmm1_gemm2_k, dim3(NV / 32), dim3(512), 0, stream,
                     XW1, cols, rowcount, dinv, diagv, W2, HW2);
  hipLaunchKernelGGL(spmm2_lsm_k, dim3(NV / 4), dim3(256), 0, stream,
                     HW2, cols, rowcount, dinv, diagv, out);
}